// Round 7
// baseline (205.579 us; speedup 1.0000x reference)
//
#include <hip/hip_runtime.h>
#include <math.h>

// MinGRU: B=8, S=8192, D=256, H=256, fp32 in/out.
//   K0 prep_bf16 : one streaming pass converts x (64->32 MiB) and both
//                  weight matrices (512->256 KiB) to row-major bf16
//                  (identical pack2bf rounding -> bit-identical GEMM).
//   K1 gemm_zh   : bf16-MFMA dual GEMM; staging is now a PURE COPY
//                  (uint4 global -> aligned 16B LDS writes, zero pack2bf
//                  in the k-loop; R5 had 48 packs/k0 = the VALU tax).
//                  Sigmoid epilogue + fused phase-A (chunk (P,Q) via
//                  ordered shfl_xor butterfly) unchanged from R3/R5.
//   K2 phaseB    : sequential scan over 128 chunk summaries (batch-16).
//   K3 phaseC    : replay; 1024 blocks x 64 thr (1 chunk/block),
//                  4 ch/thread, uint4/float4 (16B/lane).
// R4 lessons: direct-L2 weight fragments stall MFMA (keep LDS staging);
//             subchunk granularity quadruples phaseB's chain (chunks=128).
// R1/R2 lesson: register-resident scan across a grid sync always spills.
// R6: bench infra failure (container died twice, no counters); source
//     audited clean -- resubmission of the same structure.

constexpr int B_ = 8;
constexpr int S_ = 8192;
constexpr int D_ = 256;
constexpr int H_ = 256;
constexpr int M_ = B_ * S_;        // 65536 rows
constexpr int CHUNKS = 128;
constexpr int CLEN = S_ / CHUNKS;  // 64

typedef __attribute__((ext_vector_type(8))) short bf16x8;
typedef __attribute__((ext_vector_type(4))) float f32x4;

// 2 floats -> 2 bf16 (round-to-nearest, ties-away): 2 adds + 1 v_perm.
// lo16 = bf16(f0), hi16 = bf16(f1).
__device__ __forceinline__ uint pack2bf(float f0, float f1) {
  const uint u0 = __float_as_uint(f0) + 0x8000u;
  const uint u1 = __float_as_uint(f1) + 0x8000u;
  return __builtin_amdgcn_perm(u1, u0, 0x07060302u);
}

__device__ __forceinline__ float a_of(uint u) { return __uint_as_float(u << 16); }
__device__ __forceinline__ float b_of(uint u) { return __uint_as_float(u & 0xFFFF0000u); }

// ---------------------------------------------------------------- prep ----
// Blocks 0..63: weights (2 x 256x256 -> wb bf16). Blocks 64+: x panels.
// Each thread: 32B fp32 in -> 16B bf16 out, fully coalesced.
__global__ __launch_bounds__(256) void prep_bf16(
    const float* __restrict__ x, const float* __restrict__ wzw,
    const float* __restrict__ whw,
    uint4* __restrict__ xb, uint4* __restrict__ wb)
{
  const int bid = blockIdx.x;
  if (bid < 64) {
    const int u = bid * 256 + threadIdx.x;   // 0..16383 (8192 per proj)
    const int proj = u >> 13;
    const float* s = (proj ? whw : wzw) + (size_t)(u & 8191) * 8;
    wb[u] = make_uint4(pack2bf(s[0], s[1]), pack2bf(s[2], s[3]),
                       pack2bf(s[4], s[5]), pack2bf(s[6], s[7]));
  } else {
    const size_t u = (size_t)(bid - 64) * 256 + threadIdx.x;  // 0..2097151
    const float* s = x + u * 8;
    xb[u] = make_uint4(pack2bf(s[0], s[1]), pack2bf(s[2], s[3]),
                       pack2bf(s[4], s[5]), pack2bf(s[6], s[7]));
  }
}

// ---------------------------------------------------------------- GEMM ----
// Block: 256 thr = 4 waves. Tile: 128 rows x 64 h-channels, both projections.
// LDS rows padded to 72 bf16 (144B = 9x16B: uint4-aligned, conflict-free
// b128 fragment reads). Wave w: rows mb..mb+63 (one 64-step chunk),
// channels nb..nb+31.
// XB=true : x from bf16 xb, staging = pure copy (no pack in loop).
// XB=false: fallback, x packed inline from fp32 (R5 path; ws too small).
template <bool XB>
__global__ __launch_bounds__(256) void gemm_zh(
    const float* __restrict__ x, const ushort* __restrict__ xbu,
    const ushort* __restrict__ wbu,
    const float* __restrict__ whb, const float* __restrict__ wzb,
    uint* __restrict__ ab, float2* __restrict__ chunkPQ)
{
  __shared__ ushort xs[128][72];
  __shared__ ushort wzs[64][72];
  __shared__ ushort whs[64][72];

  const int tid = threadIdx.x;
  // XCD swizzle: one 128-row x-panel per XCD group -> x L2-local
  // (the 4 nt-blocks of a panel share an XCD).
  const int g    = blockIdx.x;
  const int xcd  = g & 7;
  const int loc  = g >> 3;
  const int nt   = loc & 3;
  const int panel = (loc >> 2) * 8 + xcd;
  const int m0 = panel * 128;
  const int n0 = nt * 64;

  const int lane = tid & 63;
  const int w  = tid >> 6;
  const int mb = (w & 1) * 64;
  const int nb = (w >> 1) * 32;
  const int q  = lane >> 4;
  const int cn = lane & 15;

  f32x4 accz[4][2] = {};
  f32x4 acch[4][2] = {};

  for (int k0 = 0; k0 < D_; k0 += 64) {
    __syncthreads();  // WAR guard on LDS reuse
    if (XB) {
#pragma unroll
      for (int f = 0; f < 4; f++) {  // x: 128 rows x 64 k, uint4 copy
        const int idx = tid + 256 * f;
        const int row = idx >> 3, seg = idx & 7;
        *(uint4*)&xs[row][seg * 8] =
            *(const uint4*)(xbu + (size_t)(m0 + row) * D_ + k0 + seg * 8);
      }
    } else {
#pragma unroll
      for (int f = 0; f < 8; f++) {  // x: fp32 + inline pack (fallback)
        const int idx = tid + 256 * f;
        const int row = idx >> 4, seg = idx & 15;
        float4 v = *(const float4*)(x + (size_t)(m0 + row) * D_ + k0 + seg * 4);
        *(uint2*)&xs[row][seg * 4] =
            make_uint2(pack2bf(v.x, v.y), pack2bf(v.z, v.w));
      }
    }
#pragma unroll
    for (int f = 0; f < 4; f++) {  // weights: 64 rows x 64 k x 2 proj, copy
      const int idx = tid + 256 * f;
      const int proj = idx >> 9;          // uniform per f-iteration
      const int r   = (idx >> 3) & 63, seg = idx & 7;
      const uint4 v = *(const uint4*)(wbu + (size_t)proj * H_ * D_ +
                                      (size_t)(n0 + r) * D_ + k0 + seg * 8);
      ushort* dst = proj ? &whs[r][seg * 8] : &wzs[r][seg * 8];
      *(uint4*)dst = v;
    }
    __syncthreads();
#pragma unroll
    for (int ks = 0; ks < 2; ks++) {
      const int kk = ks * 32 + q * 8;  // A[m=lane&15][k=quad*8+j]
      bf16x8 af[4], bz[2], bh[2];
#pragma unroll
      for (int i = 0; i < 4; i++)
        af[i] = *(const bf16x8*)&xs[mb + i * 16 + cn][kk];
#pragma unroll
      for (int j = 0; j < 2; j++) {
        bz[j] = *(const bf16x8*)&wzs[nb + j * 16 + cn][kk];
        bh[j] = *(const bf16x8*)&whs[nb + j * 16 + cn][kk];
      }
#pragma unroll
      for (int i = 0; i < 4; i++)
#pragma unroll
        for (int j = 0; j < 2; j++) {
          accz[i][j] = __builtin_amdgcn_mfma_f32_16x16x32_bf16(af[i], bz[j], accz[i][j], 0, 0, 0);
          acch[i][j] = __builtin_amdgcn_mfma_f32_16x16x32_bf16(af[i], bh[j], acch[i][j], 0, 0, 0);
        }
    }
  }

  // Chunk identity for this wave (chunks never cross batch: 8192%64==0).
  const int row0 = m0 + mb;
  const int bb2  = row0 >> 13;          // batch
  const int cc   = (row0 & 8191) >> 6;  // chunk within batch

  // Epilogue: C/D col=lane&15, row=quad*4+reg. a=1-z=e*rcp, b=z*h~.
  // t within chunk = i*16 + q*4 + r (ascending in i, q, r).
#pragma unroll
  for (int j = 0; j < 2; j++) {
    const int ch = n0 + nb + j * 16 + cn;
    const float zb = wzb[ch], hb = whb[ch];
    uint u[4][4];
#pragma unroll
    for (int i = 0; i < 4; i++) {
#pragma unroll
      for (int r = 0; r < 4; r++) {
        const int row = m0 + mb + i * 16 + q * 4 + r;
        const float zpre = accz[i][j][r] + zb;
        const float hpre = acch[i][j][r] + hb;
        const float e = __expf(-zpre);
        const float rcp = __builtin_amdgcn_rcpf(1.0f + e);  // z
        const uint pk = pack2bf(e * rcp, hpre * rcp);
        ab[(size_t)row * H_ + ch] = pk;
        u[i][r] = pk;
      }
    }
    // ---- fused phase A: (P,Q) over the 64-step chunk, composed from the
    // packed bf16 values in fp32 (bit-identical to a sequential scan).
    float P[4], Q[4];
#pragma unroll
    for (int i = 0; i < 4; i++) {
      float Pi = 1.f, Qi = 0.f;
#pragma unroll
      for (int r = 0; r < 4; r++) {
        const float a  = a_of(u[i][r]);
        const float bv = b_of(u[i][r]);
        Qi = fmaf(a, Qi, bv);
        Pi *= a;
      }
      P[i] = Pi; Q[i] = Qi;
    }
    // combine(first,second): P = P1*P2, Q = fma(P2, Q1, Q2). t-order aware.
#pragma unroll
    for (int i = 0; i < 4; i++) {
      {  // partner q^1 (lane^16)
        const float Pp = __shfl_xor(P[i], 16);
        const float Qp = __shfl_xor(Q[i], 16);
        const bool later = (lane & 16) != 0;
        Q[i] = later ? fmaf(P[i], Qp, Q[i]) : fmaf(Pp, Q[i], Qp);
        P[i] = P[i] * Pp;
      }
      {  // partner q^2 (lane^32)
        const float Pp = __shfl_xor(P[i], 32);
        const float Qp = __shfl_xor(Q[i], 32);
        const bool later = (lane & 32) != 0;
        Q[i] = later ? fmaf(P[i], Qp, Q[i]) : fmaf(Pp, Q[i], Qp);
        P[i] = P[i] * Pp;
      }
    }
    float Pc = P[0], Qc = Q[0];
#pragma unroll
    for (int i = 1; i < 4; i++) {
      Qc = fmaf(P[i], Qc, Q[i]);
      Pc *= P[i];
    }
    if (lane < 16)  // one lane per channel (cn==lane, q==0)
      chunkPQ[((size_t)bb2 * CHUNKS + cc) * H_ + ch] = make_float2(Pc, Qc);
  }
}

// ---------------------------------------------------------------- scans ---
// Phase B: sequential scan over chunk summaries, batch-16 float2 loads.
__global__ __launch_bounds__(256) void scan_phaseB(
    const float* __restrict__ h0in, const float2* __restrict__ pq,
    float* __restrict__ hstate)
{
  const int b = blockIdx.x;
  const int h = threadIdx.x;
  const size_t base = (size_t)b * CHUNKS * H_ + h;
  float hc = h0in[(size_t)b * H_ + h];
  for (int c0 = 0; c0 < CHUNKS; c0 += 16) {
    float2 v[16];
#pragma unroll
    for (int j = 0; j < 16; j++)
      v[j] = pq[base + (size_t)(c0 + j) * H_];
#pragma unroll
    for (int j = 0; j < 16; j++) {
      hstate[base + (size_t)(c0 + j) * H_] = hc;
      hc = fmaf(v[j].x, hc, v[j].y);
    }
  }
}

// Phase C: replay. 1024 blocks x 64 thr: block = 1 chunk, thread = 4
// channels x 64 steps. uint4 loads / float4 stores (16B/lane, coalesced).
__global__ __launch_bounds__(64) void scan_phaseC(
    const uint* __restrict__ ab, const float* __restrict__ hstate,
    float* __restrict__ out)
{
  const int cid = blockIdx.x;           // global chunk id
  const int b = cid >> 7;
  const int c = cid & (CHUNKS - 1);
  const int ch4 = threadIdx.x * 4;
  const size_t ebase = ((size_t)b * S_ + (size_t)c * CLEN) * H_ + ch4;

  float4 h4 = *(const float4*)(hstate + ((size_t)b * CHUNKS + c) * H_ + ch4);
  float h0v = h4.x, h1v = h4.y, h2v = h4.z, h3v = h4.w;

#pragma unroll
  for (int t0 = 0; t0 < CLEN; t0 += 8) {
    uint4 v[8];
#pragma unroll
    for (int j = 0; j < 8; j++)
      v[j] = *(const uint4*)(ab + ebase + (size_t)(t0 + j) * H_);
#pragma unroll
    for (int j = 0; j < 8; j++) {
      float4 o;
      o.x = h0v = fmaf(a_of(v[j].x), h0v, b_of(v[j].x));
      o.y = h1v = fmaf(a_of(v[j].y), h1v, b_of(v[j].y));
      o.z = h2v = fmaf(a_of(v[j].z), h2v, b_of(v[j].z));
      o.w = h3v = fmaf(a_of(v[j].w), h3v, b_of(v[j].w));
      *(float4*)(out + ebase + (size_t)(t0 + j) * H_) = o;
    }
  }
}

extern "C" void kernel_launch(void* const* d_in, const int* in_sizes, int n_in,
                              void* d_out, int out_size, void* d_ws, size_t ws_size,
                              hipStream_t stream) {
  const float* x   = (const float*)d_in[0];
  const float* h0  = (const float*)d_in[1];
  const float* whw = (const float*)d_in[2];
  const float* whb = (const float*)d_in[3];
  const float* wzw = (const float*)d_in[4];
  const float* wzb = (const float*)d_in[5];
  float* out = (float*)d_out;

  uint*   ab      = (uint*)d_ws;                          // [M,H] packed bf16
  float2* chunkPQ = (float2*)(ab + (size_t)M_ * H_);      // [B,CHUNKS,H]
  float*  hstate  = (float*)(chunkPQ + (size_t)B_ * CHUNKS * H_);  // [B,CHUNKS,H]
  ushort* wb      = (ushort*)(hstate + (size_t)B_ * CHUNKS * H_);  // [2,H,D] bf16
  ushort* xb      = wb + (size_t)2 * H_ * D_;             // [M,D] bf16
  const size_t ws_need = (size_t)((char*)(xb + (size_t)M_ * D_) - (char*)d_ws);

  if (ws_size >= ws_need) {
    prep_bf16<<<64 + (M_ * D_ / 8) / 256, 256, 0, stream>>>(
        x, wzw, whw, (uint4*)xb, (uint4*)wb);
    gemm_zh<true><<<(M_ / 128) * 4, 256, 0, stream>>>(
        x, xb, wb, whb, wzb, ab, chunkPQ);
  } else {
    // Weights-only prep (64 blocks never touch the xb argument).
    prep_bf16<<<64, 256, 0, stream>>>(x, wzw, whw, nullptr, (uint4*)wb);
    gemm_zh<false><<<(M_ / 128) * 4, 256, 0, stream>>>(
        x, xb, wb, whb, wzb, ab, chunkPQ);
  }
  scan_phaseB<<<B_, 256, 0, stream>>>(h0, (const float2*)chunkPQ, hstate);
  scan_phaseC<<<B_ * CHUNKS, 64, 0, stream>>>(ab, hstate, out);
}

// Round 8
// 177.177 us; speedup vs baseline: 1.1603x; 1.1603x over previous
//
#include <hip/hip_runtime.h>
#include <math.h>

// MinGRU: B=8, S=8192, D=256, H=256, fp32 in/out.
//   K0 prep_w   : weights-only fp32->bf16 (256 KiB, ~3 us).
//   K1 gemm_zh  : bf16-MFMA dual GEMM, 512 thr / 128x128 tile / 8 waves.
//                 LDS 54 KiB -> 2 blocks/CU = 16 waves/CU (2x R7 occup).
//                 x packed inline (24 pack-ops/thread/k0 -- half of R5);
//                 weights pure uint4 copy from prepped bf16.
//                 Sigmoid epilogue + fused phase-A (chunk (P,Q) via
//                 ordered shfl_xor butterfly) unchanged.
//   K2 phaseB   : sequential scan over 128 chunk summaries (batch-16).
//   K3 phaseC   : replay; 1024 blocks x 64 thr, 4 ch/thread, uint4/float4.
// R7 lesson: full x-prep is zero-sum (gemm -10us, prep +20us) -> dropped.
// R4 lessons: direct-L2 weight fragments stall MFMA (keep LDS staging);
//             subchunk granularity quadruples phaseB's chain (chunks=128).
// R1/R2 lesson: register-resident scan across a grid sync always spills.

constexpr int B_ = 8;
constexpr int S_ = 8192;
constexpr int D_ = 256;
constexpr int H_ = 256;
constexpr int M_ = B_ * S_;        // 65536 rows
constexpr int CHUNKS = 128;
constexpr int CLEN = S_ / CHUNKS;  // 64

typedef __attribute__((ext_vector_type(8))) short bf16x8;
typedef __attribute__((ext_vector_type(4))) float f32x4;

// 2 floats -> 2 bf16 (round-to-nearest, ties-away): 2 adds + 1 v_perm.
// lo16 = bf16(f0), hi16 = bf16(f1).
__device__ __forceinline__ uint pack2bf(float f0, float f1) {
  const uint u0 = __float_as_uint(f0) + 0x8000u;
  const uint u1 = __float_as_uint(f1) + 0x8000u;
  return __builtin_amdgcn_perm(u1, u0, 0x07060302u);
}

__device__ __forceinline__ float a_of(uint u) { return __uint_as_float(u << 16); }
__device__ __forceinline__ float b_of(uint u) { return __uint_as_float(u & 0xFFFF0000u); }

// ---------------------------------------------------------------- prep ----
// Weights only: 2 x 256x256 fp32 -> bf16 (identical pack2bf rounding).
__global__ __launch_bounds__(256) void prep_w(
    const float* __restrict__ wzw, const float* __restrict__ whw,
    uint4* __restrict__ wb)
{
  const int u = blockIdx.x * 256 + threadIdx.x;   // 0..16383 (8192 per proj)
  const int proj = u >> 13;
  const float* s = (proj ? whw : wzw) + (size_t)(u & 8191) * 8;
  wb[u] = make_uint4(pack2bf(s[0], s[1]), pack2bf(s[2], s[3]),
                     pack2bf(s[4], s[5]), pack2bf(s[6], s[7]));
}

// ---------------------------------------------------------------- GEMM ----
// Block: 512 thr = 8 waves. Tile: 128 rows x 128 h-channels, both proj.
// LDS rows padded to 72 bf16 (144B = 9x16B: uint4-aligned, conflict-free
// b128 fragment reads). Wave w: rows mb..mb+63 (one 64-step chunk),
// channels nb..nb+31 (nb = (w>>1)*32 over the 128-ch tile).
__global__ __launch_bounds__(512, 4) void gemm_zh(
    const float* __restrict__ x, const ushort* __restrict__ wbu,
    const float* __restrict__ whb, const float* __restrict__ wzb,
    uint* __restrict__ ab, float2* __restrict__ chunkPQ)
{
  __shared__ ushort xs[128][72];
  __shared__ ushort wzs[128][72];
  __shared__ ushort whs[128][72];

  const int tid = threadIdx.x;
  // XCD swizzle: the 2 n-tiles of a 128-row x-panel land on one XCD.
  const int g    = blockIdx.x;          // 0..1023
  const int xcd  = g & 7;
  const int loc  = g >> 3;              // 0..127
  const int nt   = loc & 1;
  const int panel = (loc >> 1) * 8 + xcd;  // 0..511
  const int m0 = panel * 128;
  const int n0 = nt * 128;

  const int lane = tid & 63;
  const int w  = tid >> 6;              // 0..7
  const int mb = (w & 1) * 64;
  const int nb = (w >> 1) * 32;         // 0,32,64,96
  const int q  = lane >> 4;
  const int cn = lane & 15;

  f32x4 accz[4][2] = {};
  f32x4 acch[4][2] = {};

  for (int k0 = 0; k0 < D_; k0 += 64) {
    __syncthreads();  // WAR guard on LDS reuse
#pragma unroll
    for (int f = 0; f < 4; f++) {  // x: 128 rows x 64 k, fp32 + inline pack
      const int idx = tid + 512 * f;
      const int row = idx >> 4, seg = idx & 15;
      float4 v = *(const float4*)(x + (size_t)(m0 + row) * D_ + k0 + seg * 4);
      *(uint2*)&xs[row][seg * 4] =
          make_uint2(pack2bf(v.x, v.y), pack2bf(v.z, v.w));
    }
#pragma unroll
    for (int f = 0; f < 4; f++) {  // weights: 128 ch x 64 k x 2 proj, copy
      const int idx = tid + 512 * f;
      const int proj = idx >> 10;        // f<2 -> 0, f>=2 -> 1 (uniform)
      const int r   = (idx >> 3) & 127, seg = idx & 7;
      const uint4 v = *(const uint4*)(wbu + (size_t)proj * H_ * D_ +
                                      (size_t)(n0 + r) * D_ + k0 + seg * 8);
      ushort* dst = proj ? &whs[r][seg * 8] : &wzs[r][seg * 8];
      *(uint4*)dst = v;
    }
    __syncthreads();
#pragma unroll
    for (int ks = 0; ks < 2; ks++) {
      const int kk = ks * 32 + q * 8;  // A[m=lane&15][k=quad*8+j]
      bf16x8 af[4], bz[2], bh[2];
#pragma unroll
      for (int i = 0; i < 4; i++)
        af[i] = *(const bf16x8*)&xs[mb + i * 16 + cn][kk];
#pragma unroll
      for (int j = 0; j < 2; j++) {
        bz[j] = *(const bf16x8*)&wzs[nb + j * 16 + cn][kk];
        bh[j] = *(const bf16x8*)&whs[nb + j * 16 + cn][kk];
      }
#pragma unroll
      for (int i = 0; i < 4; i++)
#pragma unroll
        for (int j = 0; j < 2; j++) {
          accz[i][j] = __builtin_amdgcn_mfma_f32_16x16x32_bf16(af[i], bz[j], accz[i][j], 0, 0, 0);
          acch[i][j] = __builtin_amdgcn_mfma_f32_16x16x32_bf16(af[i], bh[j], acch[i][j], 0, 0, 0);
        }
    }
  }

  // Chunk identity for this wave (chunks never cross batch: 8192%64==0).
  const int row0 = m0 + mb;
  const int bb2  = row0 >> 13;          // batch
  const int cc   = (row0 & 8191) >> 6;  // chunk within batch

  // Epilogue: C/D col=lane&15, row=quad*4+reg. a=1-z=e*rcp, b=z*h~.
  // t within chunk = i*16 + q*4 + r (ascending in i, q, r).
#pragma unroll
  for (int j = 0; j < 2; j++) {
    const int ch = n0 + nb + j * 16 + cn;
    const float zb = wzb[ch], hb = whb[ch];
    uint u[4][4];
#pragma unroll
    for (int i = 0; i < 4; i++) {
#pragma unroll
      for (int r = 0; r < 4; r++) {
        const int row = m0 + mb + i * 16 + q * 4 + r;
        const float zpre = accz[i][j][r] + zb;
        const float hpre = acch[i][j][r] + hb;
        const float e = __expf(-zpre);
        const float rcp = __builtin_amdgcn_rcpf(1.0f + e);  // z
        const uint pk = pack2bf(e * rcp, hpre * rcp);
        ab[(size_t)row * H_ + ch] = pk;
        u[i][r] = pk;
      }
    }
    // ---- fused phase A: (P,Q) over the 64-step chunk, composed from the
    // packed bf16 values in fp32 (bit-identical to a sequential scan).
    float P[4], Q[4];
#pragma unroll
    for (int i = 0; i < 4; i++) {
      float Pi = 1.f, Qi = 0.f;
#pragma unroll
      for (int r = 0; r < 4; r++) {
        const float a  = a_of(u[i][r]);
        const float bv = b_of(u[i][r]);
        Qi = fmaf(a, Qi, bv);
        Pi *= a;
      }
      P[i] = Pi; Q[i] = Qi;
    }
    // combine(first,second): P = P1*P2, Q = fma(P2, Q1, Q2). t-order aware.
#pragma unroll
    for (int i = 0; i < 4; i++) {
      {  // partner q^1 (lane^16)
        const float Pp = __shfl_xor(P[i], 16);
        const float Qp = __shfl_xor(Q[i], 16);
        const bool later = (lane & 16) != 0;
        Q[i] = later ? fmaf(P[i], Qp, Q[i]) : fmaf(Pp, Q[i], Qp);
        P[i] = P[i] * Pp;
      }
      {  // partner q^2 (lane^32)
        const float Pp = __shfl_xor(P[i], 32);
        const float Qp = __shfl_xor(Q[i], 32);
        const bool later = (lane & 32) != 0;
        Q[i] = later ? fmaf(P[i], Qp, Q[i]) : fmaf(Pp, Q[i], Qp);
        P[i] = P[i] * Pp;
      }
    }
    float Pc = P[0], Qc = Q[0];
#pragma unroll
    for (int i = 1; i < 4; i++) {
      Qc = fmaf(P[i], Qc, Q[i]);
      Pc *= P[i];
    }
    if (lane < 16)  // one lane per channel (cn==lane, q==0)
      chunkPQ[((size_t)bb2 * CHUNKS + cc) * H_ + ch] = make_float2(Pc, Qc);
  }
}

// ---------------------------------------------------------------- scans ---
// Phase B: sequential scan over chunk summaries, batch-16 float2 loads.
__global__ __launch_bounds__(256) void scan_phaseB(
    const float* __restrict__ h0in, const float2* __restrict__ pq,
    float* __restrict__ hstate)
{
  const int b = blockIdx.x;
  const int h = threadIdx.x;
  const size_t base = (size_t)b * CHUNKS * H_ + h;
  float hc = h0in[(size_t)b * H_ + h];
  for (int c0 = 0; c0 < CHUNKS; c0 += 16) {
    float2 v[16];
#pragma unroll
    for (int j = 0; j < 16; j++)
      v[j] = pq[base + (size_t)(c0 + j) * H_];
#pragma unroll
    for (int j = 0; j < 16; j++) {
      hstate[base + (size_t)(c0 + j) * H_] = hc;
      hc = fmaf(v[j].x, hc, v[j].y);
    }
  }
}

// Phase C: replay. 1024 blocks x 64 thr: block = 1 chunk, thread = 4
// channels x 64 steps. uint4 loads / float4 stores (16B/lane, coalesced).
__global__ __launch_bounds__(64) void scan_phaseC(
    const uint* __restrict__ ab, const float* __restrict__ hstate,
    float* __restrict__ out)
{
  const int cid = blockIdx.x;           // global chunk id
  const int b = cid >> 7;
  const int c = cid & (CHUNKS - 1);
  const int ch4 = threadIdx.x * 4;
  const size_t ebase = ((size_t)b * S_ + (size_t)c * CLEN) * H_ + ch4;

  float4 h4 = *(const float4*)(hstate + ((size_t)b * CHUNKS + c) * H_ + ch4);
  float h0v = h4.x, h1v = h4.y, h2v = h4.z, h3v = h4.w;

#pragma unroll
  for (int t0 = 0; t0 < CLEN; t0 += 8) {
    uint4 v[8];
#pragma unroll
    for (int j = 0; j < 8; j++)
      v[j] = *(const uint4*)(ab + ebase + (size_t)(t0 + j) * H_);
#pragma unroll
    for (int j = 0; j < 8; j++) {
      float4 o;
      o.x = h0v = fmaf(a_of(v[j].x), h0v, b_of(v[j].x));
      o.y = h1v = fmaf(a_of(v[j].y), h1v, b_of(v[j].y));
      o.z = h2v = fmaf(a_of(v[j].z), h2v, b_of(v[j].z));
      o.w = h3v = fmaf(a_of(v[j].w), h3v, b_of(v[j].w));
      *(float4*)(out + ebase + (size_t)(t0 + j) * H_) = o;
    }
  }
}

extern "C" void kernel_launch(void* const* d_in, const int* in_sizes, int n_in,
                              void* d_out, int out_size, void* d_ws, size_t ws_size,
                              hipStream_t stream) {
  const float* x   = (const float*)d_in[0];
  const float* h0  = (const float*)d_in[1];
  const float* whw = (const float*)d_in[2];
  const float* whb = (const float*)d_in[3];
  const float* wzw = (const float*)d_in[4];
  const float* wzb = (const float*)d_in[5];
  float* out = (float*)d_out;

  uint*   ab      = (uint*)d_ws;                          // [M,H] packed bf16
  float2* chunkPQ = (float2*)(ab + (size_t)M_ * H_);      // [B,CHUNKS,H]
  float*  hstate  = (float*)(chunkPQ + (size_t)B_ * CHUNKS * H_);  // [B,CHUNKS,H]
  ushort* wb      = (ushort*)(hstate + (size_t)B_ * CHUNKS * H_);  // [2,H,D] bf16

  prep_w<<<64, 256, 0, stream>>>(wzw, whw, (uint4*)wb);
  gemm_zh<<<(M_ / 128) * (H_ / 128), 512, 0, stream>>>(
      x, wb, whb, wzb, ab, chunkPQ);
  scan_phaseB<<<B_, 256, 0, stream>>>(h0, (const float2*)chunkPQ, hstate);
  scan_phaseC<<<B_ * CHUNKS, 64, 0, stream>>>(ab, hstate, out);
}